// Round 1
// baseline (115.255 us; speedup 1.0000x reference)
//
#include <hip/hip_runtime.h>

#define B_   64
#define T_   2000
#define RNN_ 1024
#define EMB_ 512
#define ATT_ 128
#define CH_  8
#define K_   21
#define PL_  11
#define GSZ  168   // CH_*K_
#define TCH  125   // T-chunk per context block (16 chunks)

__device__ __forceinline__ float fast_tanh(float x) {
    float ax = fabsf(x);
    float e  = __expf(2.0f * ax);
    float t  = 1.0f - 2.0f / (e + 1.0f);
    return copysignf(t, x);
}

// ---- kernel 1: G = tanh(q @ W_w^T + W_b) @ V_w^T  -> [B,168] ----
__global__ __launch_bounds__(256) void k_gen_dyn(
    const float* __restrict__ q, const float* __restrict__ Ww,
    const float* __restrict__ Wb, const float* __restrict__ Vw,
    float* __restrict__ G)
{
    __shared__ float sq[RNN_];
    __shared__ float sh[ATT_];
    const int b = blockIdx.x, tid = threadIdx.x;
    for (int i = tid; i < RNN_; i += 256) sq[i] = q[b * RNN_ + i];
    __syncthreads();
    if (tid < ATT_) {
        const float4* wr = reinterpret_cast<const float4*>(Ww + tid * RNN_);
        const float4* qr = reinterpret_cast<const float4*>(sq);
        float acc = 0.f;
        #pragma unroll 8
        for (int i = 0; i < RNN_ / 4; ++i) {
            float4 w4 = wr[i], q4 = qr[i];
            acc += w4.x * q4.x + w4.y * q4.y + w4.z * q4.z + w4.w * q4.w;
        }
        sh[tid] = fast_tanh(acc + Wb[tid]);
    }
    __syncthreads();
    for (int o = tid; o < GSZ; o += 256) {
        const float4* vr = reinterpret_cast<const float4*>(Vw + o * ATT_);
        const float4* hr = reinterpret_cast<const float4*>(sh);
        float acc = 0.f;
        #pragma unroll 8
        for (int i = 0; i < ATT_ / 4; ++i) {
            float4 v4 = vr[i], h4 = hr[i];
            acc += v4.x * h4.x + v4.y * h4.y + v4.z * h4.z + v4.w * h4.w;
        }
        G[b * GSZ + o] = acc;
    }
}

// ---- kernel 2: fused convs + prior + tanh-MLP -> e[b,t] (staged in out_w) ----
__global__ __launch_bounds__(256) void k_energy(
    const float* __restrict__ a,  const float* __restrict__ G,
    const float* __restrict__ Fw, const float* __restrict__ Uw,
    const float* __restrict__ Tw, const float* __restrict__ Tb,
    const float* __restrict__ vw, const float* __restrict__ P,
    float* __restrict__ eout)
{
    __shared__ float sA[256 + K_ - 1];   // 276 window
    __shared__ float sFG[K_ * 16];       // [k][16]: c<8 = F_w[c][k], c>=8 = G[b][(c-8)*21+k]
    __shared__ float sUT[ATT_ * 16];     // [d][16]: c<8 = U_w[d][c], c>=8 = T_w[d][c-8]
    __shared__ float sTb[ATT_], sV[ATT_], sP[PL_];
    const int b = blockIdx.x, tid = threadIdx.x;
    const int t0 = blockIdx.y * 256;
    const int base = t0 - (K_ - 1) / 2;  // t0 - 10

    for (int j = tid; j < 256 + K_ - 1; j += 256) {
        int idx = base + j;
        sA[j] = (idx >= 0 && idx < T_) ? a[b * T_ + idx] : 0.f;
    }
    for (int j = tid; j < 2 * GSZ; j += 256) {
        if (j < GSZ) sFG[(j % K_) * 16 + (j / K_)] = Fw[j];
        else { int jj = j - GSZ; sFG[(jj % K_) * 16 + 8 + (jj / K_)] = G[b * GSZ + jj]; }
    }
    for (int j = tid; j < ATT_ * CH_; j += 256) {
        int d = j >> 3, c = j & 7;
        sUT[d * 16 + c]     = Uw[j];
        sUT[d * 16 + 8 + c] = Tw[j];
    }
    if (tid < ATT_) { sTb[tid] = Tb[tid]; sV[tid] = vw[tid]; }
    if (tid < PL_)  sP[tid] = P[tid];
    __syncthreads();

    float fg[16];
    #pragma unroll
    for (int i = 0; i < 16; ++i) fg[i] = 0.f;
    #pragma unroll
    for (int k = 0; k < K_; ++k) {
        float av = sA[tid + k];
        const float4* fp = reinterpret_cast<const float4*>(&sFG[k * 16]);
        float4 x0 = fp[0], x1 = fp[1], x2 = fp[2], x3 = fp[3];
        fg[0]  += x0.x * av; fg[1]  += x0.y * av; fg[2]  += x0.z * av; fg[3]  += x0.w * av;
        fg[4]  += x1.x * av; fg[5]  += x1.y * av; fg[6]  += x1.z * av; fg[7]  += x1.w * av;
        fg[8]  += x2.x * av; fg[9]  += x2.y * av; fg[10] += x2.z * av; fg[11] += x2.w * av;
        fg[12] += x3.x * av; fg[13] += x3.y * av; fg[14] += x3.z * av; fg[15] += x3.w * av;
    }
    float pp = 0.f;
    #pragma unroll
    for (int k = 0; k < PL_; ++k) pp += sP[k] * sA[tid + k];

    float acc = 0.f;
    #pragma unroll 4
    for (int d = 0; d < ATT_; ++d) {
        const float4* up = reinterpret_cast<const float4*>(&sUT[d * 16]);
        float4 u0 = up[0], u1 = up[1], u2 = up[2], u3 = up[3];
        float s = sTb[d];
        s += u0.x * fg[0]  + u0.y * fg[1]  + u0.z * fg[2]  + u0.w * fg[3];
        s += u1.x * fg[4]  + u1.y * fg[5]  + u1.z * fg[6]  + u1.w * fg[7];
        s += u2.x * fg[8]  + u2.y * fg[9]  + u2.z * fg[10] + u2.w * fg[11];
        s += u3.x * fg[12] + u3.y * fg[13] + u3.z * fg[14] + u3.w * fg[15];
        acc += sV[d] * fast_tanh(s);
    }
    const int t = t0 + tid;
    if (t < T_) eout[b * T_ + t] = acc + __logf(fmaxf(pp, 1e-6f));
}

// ---- kernel 3: in-place softmax over T per batch (e -> w) ----
__global__ __launch_bounds__(256) void k_softmax(
    float* __restrict__ w, const unsigned char* __restrict__ mask)
{
    __shared__ float buf[T_];
    __shared__ float red[4];
    const int b = blockIdx.x, tid = threadIdx.x;
    float* wb = w + b * T_;
    const unsigned char* mb = mask + b * T_;
    float m = -1e30f;
    for (int t = tid; t < T_; t += 256) {
        float v = wb[t];
        if (mb[t]) v = -1e30f;
        buf[t] = v;
        m = fmaxf(m, v);
    }
    #pragma unroll
    for (int off = 32; off > 0; off >>= 1) m = fmaxf(m, __shfl_down(m, off));
    if ((tid & 63) == 0) red[tid >> 6] = m;
    __syncthreads();
    float M = fmaxf(fmaxf(red[0], red[1]), fmaxf(red[2], red[3]));
    __syncthreads();
    float s = 0.f;
    for (int t = tid; t < T_; t += 256) {
        float ex = __expf(buf[t] - M);
        buf[t] = ex;
        s += ex;
    }
    #pragma unroll
    for (int off = 32; off > 0; off >>= 1) s += __shfl_down(s, off);
    if ((tid & 63) == 0) red[tid >> 6] = s;
    __syncthreads();
    float inv = 1.0f / (red[0] + red[1] + red[2] + red[3]);
    for (int t = tid; t < T_; t += 256) wb[t] = buf[t] * inv;
}

// ---- kernel 4: context = sum_t w[b,t] * memory[b,t,:] (atomic merge over 16 chunks) ----
__global__ __launch_bounds__(128) void k_ctx(
    const float* __restrict__ w, const float* __restrict__ mem,
    float* __restrict__ out)
{
    __shared__ float sw[TCH];
    const int b = blockIdx.x, chunk = blockIdx.y, tid = threadIdx.x;
    const int t0 = chunk * TCH;
    if (tid < TCH) sw[tid] = w[b * T_ + t0 + tid];
    __syncthreads();
    const float4* m4 = reinterpret_cast<const float4*>(mem + ((size_t)(b * T_ + t0)) * EMB_) + tid;
    float ax = 0.f, ay = 0.f, az = 0.f, aw = 0.f;
    #pragma unroll 5
    for (int tt = 0; tt < TCH; ++tt) {
        float wv = sw[tt];
        float4 mv = m4[(size_t)tt * (EMB_ / 4)];
        ax += wv * mv.x; ay += wv * mv.y; az += wv * mv.z; aw += wv * mv.w;
    }
    float* op = out + b * EMB_ + tid * 4;
    atomicAdd(op + 0, ax); atomicAdd(op + 1, ay);
    atomicAdd(op + 2, az); atomicAdd(op + 3, aw);
}

extern "C" void kernel_launch(void* const* d_in, const int* in_sizes, int n_in,
                              void* d_out, int out_size, void* d_ws, size_t ws_size,
                              hipStream_t stream)
{
    const float* q    = (const float*)d_in[0];
    const float* mem  = (const float*)d_in[1];
    const float* a    = (const float*)d_in[2];
    const unsigned char* mask = (const unsigned char*)d_in[3];
    const float* Ww = (const float*)d_in[4];
    const float* Wb = (const float*)d_in[5];
    const float* Vw = (const float*)d_in[6];
    const float* Fw = (const float*)d_in[7];
    const float* Uw = (const float*)d_in[8];
    const float* Tw = (const float*)d_in[9];
    const float* Tb = (const float*)d_in[10];
    const float* vw = (const float*)d_in[11];
    const float* P  = (const float*)d_in[12];

    float* out_ctx = (float*)d_out;           // [64*512]
    float* out_w   = out_ctx + B_ * EMB_;     // [64*2000] (energies staged, then weights)
    float* G       = (float*)d_ws;            // [64*168]

    hipMemsetAsync(out_ctx, 0, B_ * EMB_ * sizeof(float), stream);
    k_gen_dyn<<<B_, 256, 0, stream>>>(q, Ww, Wb, Vw, G);
    k_energy<<<dim3(B_, (T_ + 255) / 256), 256, 0, stream>>>(a, G, Fw, Uw, Tw, Tb, vw, P, out_w);
    k_softmax<<<B_, 256, 0, stream>>>(out_w, mask);
    k_ctx<<<dim3(B_, T_ / TCH), 128, 0, stream>>>(out_w, mem, out_ctx);
}

// Round 2
// 107.242 us; speedup vs baseline: 1.0747x; 1.0747x over previous
//
#include <hip/hip_runtime.h>

#define B_   64
#define T_   2000
#define RNN_ 1024
#define EMB_ 512
#define ATT_ 128
#define CH_  8
#define K_   21
#define PL_  11
#define GSZ  168   // CH_*K_
#define TCH  50    // T-chunk per context block (40 chunks)

typedef float vf4 __attribute__((ext_vector_type(4)));

__device__ __forceinline__ float fast_tanh(float x) {
    float ax = fabsf(x);
    float e  = __expf(2.0f * ax);
    float t  = 1.0f - 2.0f / (e + 1.0f);
    return copysignf(t, x);
}

// ---- kernel 1: G = tanh(q @ W_w^T + W_b) @ V_w^T  -> [B,168] ----
__global__ __launch_bounds__(256) void k_gen_dyn(
    const float* __restrict__ q, const float* __restrict__ Ww,
    const float* __restrict__ Wb, const float* __restrict__ Vw,
    float* __restrict__ G)
{
    __shared__ float sq[RNN_];
    __shared__ float part[256];
    __shared__ float sh[ATT_];
    const int b = blockIdx.x, tid = threadIdx.x;
    for (int i = tid; i < RNN_; i += 256) sq[i] = q[b * RNN_ + i];
    __syncthreads();
    {
        const int row = tid & 127, half = tid >> 7;        // 2-way K split
        const float4* wr = reinterpret_cast<const float4*>(Ww + row * RNN_ + half * (RNN_ / 2));
        const float4* qr = reinterpret_cast<const float4*>(sq + half * (RNN_ / 2));
        float acc = 0.f;
        #pragma unroll 8
        for (int i = 0; i < RNN_ / 8; ++i) {
            float4 w4 = wr[i], q4 = qr[i];
            acc += w4.x * q4.x + w4.y * q4.y + w4.z * q4.z + w4.w * q4.w;
        }
        part[tid] = acc;
    }
    __syncthreads();
    if (tid < ATT_) sh[tid] = fast_tanh(part[tid] + part[tid + 128] + Wb[tid]);
    __syncthreads();
    for (int o = tid; o < GSZ; o += 256) {
        const float4* vr = reinterpret_cast<const float4*>(Vw + o * ATT_);
        const float4* hr = reinterpret_cast<const float4*>(sh);
        float acc = 0.f;
        #pragma unroll 8
        for (int i = 0; i < ATT_ / 4; ++i) {
            float4 v4 = vr[i], h4 = hr[i];
            acc += v4.x * h4.x + v4.y * h4.y + v4.z * h4.z + v4.w * h4.w;
        }
        G[b * GSZ + o] = acc;
    }
}

// ---- kernel 2: fused convs + prior + tanh-MLP -> e[b,t] (staged in out_w) ----
__global__ __launch_bounds__(256) void k_energy(
    const float* __restrict__ a,  const float* __restrict__ G,
    const float* __restrict__ Fw, const float* __restrict__ Uw,
    const float* __restrict__ Tw, const float* __restrict__ Tb,
    const float* __restrict__ vw, const float* __restrict__ P,
    float* __restrict__ eout)
{
    __shared__ float sA[256 + K_ - 1];   // 276 window
    __shared__ float sFG[K_ * 16];       // [k][16]: c<8 = F_w[c][k], c>=8 = G[b][(c-8)*21+k]
    __shared__ float sUT[ATT_ * 16];     // [d][16]: c<8 = U_w[d][c], c>=8 = T_w[d][c-8]
    __shared__ float sTb[ATT_], sV[ATT_], sP[PL_];
    const int b = blockIdx.x, tid = threadIdx.x;
    const int t0 = blockIdx.y * 256;
    const int base = t0 - (K_ - 1) / 2;  // t0 - 10

    for (int j = tid; j < 256 + K_ - 1; j += 256) {
        int idx = base + j;
        sA[j] = (idx >= 0 && idx < T_) ? a[b * T_ + idx] : 0.f;
    }
    for (int j = tid; j < 2 * GSZ; j += 256) {
        if (j < GSZ) sFG[(j % K_) * 16 + (j / K_)] = Fw[j];
        else { int jj = j - GSZ; sFG[(jj % K_) * 16 + 8 + (jj / K_)] = G[b * GSZ + jj]; }
    }
    for (int j = tid; j < ATT_ * CH_; j += 256) {
        int d = j >> 3, c = j & 7;
        sUT[d * 16 + c]     = Uw[j];
        sUT[d * 16 + 8 + c] = Tw[j];
    }
    if (tid < ATT_) { sTb[tid] = Tb[tid]; sV[tid] = vw[tid]; }
    if (tid < PL_)  sP[tid] = P[tid];
    __syncthreads();

    float fg[16];
    #pragma unroll
    for (int i = 0; i < 16; ++i) fg[i] = 0.f;
    #pragma unroll
    for (int k = 0; k < K_; ++k) {
        float av = sA[tid + k];
        const float4* fp = reinterpret_cast<const float4*>(&sFG[k * 16]);
        float4 x0 = fp[0], x1 = fp[1], x2 = fp[2], x3 = fp[3];
        fg[0]  += x0.x * av; fg[1]  += x0.y * av; fg[2]  += x0.z * av; fg[3]  += x0.w * av;
        fg[4]  += x1.x * av; fg[5]  += x1.y * av; fg[6]  += x1.z * av; fg[7]  += x1.w * av;
        fg[8]  += x2.x * av; fg[9]  += x2.y * av; fg[10] += x2.z * av; fg[11] += x2.w * av;
        fg[12] += x3.x * av; fg[13] += x3.y * av; fg[14] += x3.z * av; fg[15] += x3.w * av;
    }
    float pp = 0.f;
    #pragma unroll
    for (int k = 0; k < PL_; ++k) pp += sP[k] * sA[tid + k];

    float acc = 0.f;
    #pragma unroll 4
    for (int d = 0; d < ATT_; ++d) {
        const float4* up = reinterpret_cast<const float4*>(&sUT[d * 16]);
        float4 u0 = up[0], u1 = up[1], u2 = up[2], u3 = up[3];
        float s = sTb[d];
        s += u0.x * fg[0]  + u0.y * fg[1]  + u0.z * fg[2]  + u0.w * fg[3];
        s += u1.x * fg[4]  + u1.y * fg[5]  + u1.z * fg[6]  + u1.w * fg[7];
        s += u2.x * fg[8]  + u2.y * fg[9]  + u2.z * fg[10] + u2.w * fg[11];
        s += u3.x * fg[12] + u3.y * fg[13] + u3.z * fg[14] + u3.w * fg[15];
        acc += sV[d] * fast_tanh(s);
    }
    const int t = t0 + tid;
    if (t < T_) eout[b * T_ + t] = acc + __logf(fmaxf(pp, 1e-6f));
}

// ---- kernel 3: in-place softmax over T per batch (e -> w) ----
__global__ __launch_bounds__(512) void k_softmax(
    float* __restrict__ w, const unsigned char* __restrict__ mask)
{
    __shared__ float buf[T_];
    __shared__ float red[8];
    const int b = blockIdx.x, tid = threadIdx.x;
    float* wb = w + b * T_;
    const unsigned char* mb = mask + b * T_;
    float m = -1e30f;
    for (int t = tid; t < T_; t += 512) {
        float v = wb[t];
        if (mb[t]) v = -1e30f;
        buf[t] = v;
        m = fmaxf(m, v);
    }
    #pragma unroll
    for (int off = 32; off > 0; off >>= 1) m = fmaxf(m, __shfl_down(m, off));
    if ((tid & 63) == 0) red[tid >> 6] = m;
    __syncthreads();
    float M = red[0];
    #pragma unroll
    for (int i = 1; i < 8; ++i) M = fmaxf(M, red[i]);
    __syncthreads();
    float s = 0.f;
    for (int t = tid; t < T_; t += 512) {
        float ex = __expf(buf[t] - M);
        buf[t] = ex;
        s += ex;
    }
    #pragma unroll
    for (int off = 32; off > 0; off >>= 1) s += __shfl_down(s, off);
    if ((tid & 63) == 0) red[tid >> 6] = s;
    __syncthreads();
    float S = 0.f;
    #pragma unroll
    for (int i = 0; i < 8; ++i) S += red[i];
    float inv = 1.0f / S;
    for (int t = tid; t < T_; t += 512) wb[t] = buf[t] * inv;
}

// ---- kernel 4: context = sum_t w[b,t] * memory[b,t,:] (atomic merge over 40 chunks) ----
__global__ __launch_bounds__(128) void k_ctx(
    const float* __restrict__ w, const float* __restrict__ mem,
    float* __restrict__ out)
{
    __shared__ float sw[TCH];
    const int b = blockIdx.x, chunk = blockIdx.y, tid = threadIdx.x;
    const int t0 = chunk * TCH;
    if (tid < TCH) sw[tid] = w[b * T_ + t0 + tid];
    __syncthreads();
    const vf4* m4 = reinterpret_cast<const vf4*>(mem + ((size_t)(b * T_ + t0)) * EMB_) + tid;
    float ax = 0.f, ay = 0.f, az = 0.f, aw = 0.f;
    #pragma unroll 10
    for (int tt = 0; tt < TCH; ++tt) {
        float wv = sw[tt];
        vf4 mv = __builtin_nontemporal_load(m4 + (size_t)tt * (EMB_ / 4));
        ax += wv * mv.x; ay += wv * mv.y; az += wv * mv.z; aw += wv * mv.w;
    }
    float* op = out + b * EMB_ + tid * 4;
    atomicAdd(op + 0, ax); atomicAdd(op + 1, ay);
    atomicAdd(op + 2, az); atomicAdd(op + 3, aw);
}

extern "C" void kernel_launch(void* const* d_in, const int* in_sizes, int n_in,
                              void* d_out, int out_size, void* d_ws, size_t ws_size,
                              hipStream_t stream)
{
    const float* q    = (const float*)d_in[0];
    const float* mem  = (const float*)d_in[1];
    const float* a    = (const float*)d_in[2];
    const unsigned char* mask = (const unsigned char*)d_in[3];
    const float* Ww = (const float*)d_in[4];
    const float* Wb = (const float*)d_in[5];
    const float* Vw = (const float*)d_in[6];
    const float* Fw = (const float*)d_in[7];
    const float* Uw = (const float*)d_in[8];
    const float* Tw = (const float*)d_in[9];
    const float* Tb = (const float*)d_in[10];
    const float* vw = (const float*)d_in[11];
    const float* P  = (const float*)d_in[12];

    float* out_ctx = (float*)d_out;           // [64*512]
    float* out_w   = out_ctx + B_ * EMB_;     // [64*2000] (energies staged, then weights)
    float* G       = (float*)d_ws;            // [64*168]

    hipMemsetAsync(out_ctx, 0, B_ * EMB_ * sizeof(float), stream);
    k_gen_dyn<<<B_, 256, 0, stream>>>(q, Ww, Wb, Vw, G);
    k_energy<<<dim3(B_, (T_ + 255) / 256), 256, 0, stream>>>(a, G, Fw, Uw, Tw, Tb, vw, P, out_w);
    k_softmax<<<B_, 512, 0, stream>>>(out_w, mask);
    k_ctx<<<dim3(B_, T_ / TCH), 128, 0, stream>>>(out_w, mem, out_ctx);
}